// Round 1
// baseline (175.569 us; speedup 1.0000x reference)
//
#include <hip/hip_runtime.h>

#define NEGSLOPE 0.2f
#define NINF (-3.4e38f)

typedef _Float16 half8 __attribute__((ext_vector_type(8)));
typedef float f32x4 __attribute__((ext_vector_type(4)));
typedef unsigned long long u64;

#define YSTRIDE 72  // f16 units; row stride 144 B (16B-aligned for b128)

__device__ __forceinline__ half8 h8zero() {
    half8 z;
#pragma unroll
    for (int i = 0; i < 8; ++i) z[i] = (_Float16)0.f;
    return z;
}

__device__ __forceinline__ unsigned umin(unsigned a, unsigned b) { return a < b ? a : b; }
__device__ __forceinline__ unsigned umax(unsigned a, unsigned b) { return a > b ? a : b; }

__device__ __forceinline__ int lanes_below(u64 m) {
    return __builtin_amdgcn_mbcnt_hi((unsigned)(m >> 32),
           __builtin_amdgcn_mbcnt_lo((unsigned)m, 0u));
}

// branchless sorted top-4 insert; dropped element feeds g5 (5th-smallest guard)
__device__ __forceinline__ void insert4(unsigned& r0, unsigned& r1, unsigned& r2,
                                        unsigned& r3, unsigned& g5, unsigned p) {
    unsigned q0 = umin(r0, p); p = umax(r0, p); r0 = q0;
    unsigned q1 = umin(r1, p); p = umax(r1, p); r1 = q1;
    unsigned q2 = umin(r2, p); p = umax(r2, p); r2 = q2;
    unsigned q3 = umin(r3, p); p = umax(r3, p); r3 = q3;
    g5 = umin(g5, p);
}

// ---------------------------------------------------------------------------
// topk v13 (RADIX-SELECT, 2 rows/wave): one wave handles rows (n0, n0+1) of
// one batch -- the 3x2048 slab loads are shared between both rows (halves
// load count vs v12) and the two insert chains give 2x ILP. Candidate key
// unchanged: (bits(d^2) & ~2047) | j  (d^2 >= 0 so float bits u32-ordered;
// low 11 mantissa bits traded for j => unique keys). Scan: per-lane sorted
// top-4 + g5k guard, per row. Merge: instead of a 256-element bitonic
// (21 serial cross-lane shfl substeps), find T = 20th-smallest kept key by
// 31-bit greedy radix-select: T = max v with count(kept < v) <= 19, counts
// via __ballot + popcount (scalar pipe, zero DS ops, A/B rows interleaved
// for ILP). Output = all kept keys <= T, positions via mbcnt prefix
// (unsorted -- downstream max over k is order-invariant). Exactness guard
// and rare exact fallback (~0.1% rows) identical to v12.
// Blocks >= 2048: prep path (w1g, w0f, xt) unchanged.
// ---------------------------------------------------------------------------
template <int CTRL>
__device__ __forceinline__ unsigned dpp_movm(unsigned v) {
    return (unsigned)__builtin_amdgcn_update_dpp(-1, (int)v, CTRL, 0xF, 0xF, false);
}

__global__ __launch_bounds__(256) void topk_kernel(
    const float* __restrict__ x, int* __restrict__ idx_out,
    const float* __restrict__ w1, _Float16* __restrict__ w1g,
    const float* __restrict__ w0, _Float16* __restrict__ w0f,
    f32x4* __restrict__ xt) {
    if (blockIdx.x >= 2048) {
        const int pid = blockIdx.x - 2048;   // 0..7
        int tid = pid * 256 + threadIdx.x;
#pragma unroll
        for (int it = 0; it < 12; ++it, tid += 2048) {
            int j = tid & 7;
            int L = (tid >> 3) & 63;
            int r = tid >> 9;          // r = ks*4 + t4
            int t4 = r & 3;
            int ks = r >> 2;
            int q = L >> 4, c = L & 15;
            int i = ks >> 1;
            int o = 32 * (ks & 1) + 8 * q + j;
            int u = 16 * t4 + c;
            w1g[tid] = (_Float16)w1[(u * 6 + i) * 64 + o];
        }
        if (pid == 0) {
#pragma unroll
            for (int s = 0; s < 2; ++s) {
                int t2 = threadIdx.x * 2 + s;
                int r8 = t2 >> 3, j = t2 & 7;
                w0f[t2] = (j < 6) ? (_Float16)w0[r8 * 6 + j] : (_Float16)0.f;
            }
        }
        int base = pid * 2048;
#pragma unroll
        for (int it = 0; it < 8; ++it) {
            int i = base + it * 256 + threadIdx.x;
            int bb = i >> 11, n = i & 2047;
            const float* xbp = x + bb * 6144;
            xt[i] = (f32x4){xbp[n], xbp[2048 + n], xbp[4096 + n], 0.f};
        }
        return;
    }

    const int wave = threadIdx.x >> 6;
    const int lane = threadIdx.x & 63;
    const int pr = blockIdx.x * 4 + wave;   // 0..8191, one wave = 2 rows
    const int b = pr >> 10;                 // 1024 pairs per batch
    const int n0 = (pr & 1023) * 2;         // even row of the pair
    const float* xb = x + b * 6144;
    const float ax = xb[n0],     ay = xb[2048 + n0], az = xb[4096 + n0];
    const float bx = xb[n0 + 1], by = xb[2049 + n0], bz = xb[4097 + n0];

    unsigned A0 = ~0u, A1 = ~0u, A2 = ~0u, A3 = ~0u, g5A = ~0u;
    unsigned B0 = ~0u, B1 = ~0u, B2 = ~0u, B3 = ~0u, g5B = ~0u;

#pragma unroll
    for (int t = 0; t < 32; ++t) {
        const int j = t * 64 + lane;
        const float x0 = xb[j], x1 = xb[2048 + j], x2 = xb[4096 + j];
        const float dxa = x0 - ax, dya = x1 - ay, dza = x2 - az;
        const float dxb = x0 - bx, dyb = x1 - by, dzb = x2 - bz;
        const float dA = dxa * dxa + dya * dya + dza * dza;
        const float dB = dxb * dxb + dyb * dyb + dzb * dzb;
        const unsigned pA = (__float_as_uint(dA) & 0xFFFFF800u) | (unsigned)j;
        const unsigned pB = (__float_as_uint(dB) & 0xFFFFF800u) | (unsigned)j;
        insert4(A0, A1, A2, A3, g5A, pA);
        insert4(B0, B1, B2, B3, g5B, pB);
    }

    // ---- radix-select: T = max v with count(kept < v) <= 19  (== 20th-
    // smallest kept key; exact since keys are unique). bit31 = sign of d^2,
    // always 0. A/B chains interleaved; counts live on the scalar pipe. ----
    unsigned TA = 0u, TB = 0u;
#pragma unroll 1
    for (int bit = 30; bit >= 0; --bit) {
        const unsigned cA = TA | (1u << bit);
        const unsigned cB = TB | (1u << bit);
        const int ca = __popcll(__ballot(A0 < cA)) + __popcll(__ballot(A1 < cA)) +
                       __popcll(__ballot(A2 < cA)) + __popcll(__ballot(A3 < cA));
        const int cb = __popcll(__ballot(B0 < cB)) + __popcll(__ballot(B1 < cB)) +
                       __popcll(__ballot(B2 < cB)) + __popcll(__ballot(B3 < cB));
        if (ca <= 19) TA = cA;
        if (cb <= 19) TB = cB;
    }

    const int obA = (b * 2048 + n0) * 20;
    const int obB = obA + 20;
    const u64 badA = __ballot(g5A < TA);   // discarded value inside true top-20
    const u64 badB = __ballot(g5B < TB);

    // exact fallback (rare, ~0.1% of rows): 20 rounds of recompute + DPP-min
    auto fallback = [&](float cx, float cy, float cz, int ob) {
        unsigned Tprev = 0u;
#pragma unroll 1
        for (int r = 0; r < 20; ++r) {
            unsigned best = 0xFFFFFFFFu;
#pragma unroll
            for (int t = 0; t < 32; ++t) {
                const int j = t * 64 + lane;
                const float dx = xb[j] - cx;
                const float dy = xb[2048 + j] - cy;
                const float dz = xb[4096 + j] - cz;
                const float d = dx * dx + dy * dy + dz * dz;
                const unsigned p = (__float_as_uint(d) & 0xFFFFF800u) | (unsigned)j;
                const bool ok = (r == 0) || (p > Tprev);
                best = umin(best, ok ? p : 0xFFFFFFFFu);
            }
            { unsigned o = dpp_movm<0x111>(best); best = umin(best, o); }
            { unsigned o = dpp_movm<0x112>(best); best = umin(best, o); }
            { unsigned o = dpp_movm<0x114>(best); best = umin(best, o); }
            { unsigned o = dpp_movm<0x118>(best); best = umin(best, o); }
            { unsigned o = dpp_movm<0x142>(best); best = umin(best, o); }
            { unsigned o = dpp_movm<0x143>(best); best = umin(best, o); }
            const unsigned K = (unsigned)__builtin_amdgcn_readlane((int)best, 63);
            if (lane == 0) idx_out[ob + r] = (int)(K & 2047u);
            Tprev = K;
        }
    };

    if (badA == 0) {
        const u64 m0 = __ballot(A0 <= TA), m1 = __ballot(A1 <= TA);
        const u64 m2 = __ballot(A2 <= TA), m3 = __ballot(A3 <= TA);
        const int s1 = __popcll(m0);
        const int s2 = s1 + __popcll(m1);
        const int s3 = s2 + __popcll(m2);
        if (A0 <= TA) idx_out[obA + lanes_below(m0)] = (int)(A0 & 2047u);
        if (A1 <= TA) idx_out[obA + s1 + lanes_below(m1)] = (int)(A1 & 2047u);
        if (A2 <= TA) idx_out[obA + s2 + lanes_below(m2)] = (int)(A2 & 2047u);
        if (A3 <= TA) idx_out[obA + s3 + lanes_below(m3)] = (int)(A3 & 2047u);
    } else {
        fallback(ax, ay, az, obA);
    }

    if (badB == 0) {
        const u64 m0 = __ballot(B0 <= TB), m1 = __ballot(B1 <= TB);
        const u64 m2 = __ballot(B2 <= TB), m3 = __ballot(B3 <= TB);
        const int s1 = __popcll(m0);
        const int s2 = s1 + __popcll(m1);
        const int s3 = s2 + __popcll(m2);
        if (B0 <= TB) idx_out[obB + lanes_below(m0)] = (int)(B0 & 2047u);
        if (B1 <= TB) idx_out[obB + s1 + lanes_below(m1)] = (int)(B1 & 2047u);
        if (B2 <= TB) idx_out[obB + s2 + lanes_below(m2)] = (int)(B2 & 2047u);
        if (B3 <= TB) idx_out[obB + s3 + lanes_below(m3)] = (int)(B3 & 2047u);
    } else {
        fallback(bx, by, bz, obB);
    }
}

// ---------------------------------------------------------------------------
// mlp v3 (FROZEN, R10/R12-identical): e-stage b128 gathers from xt,
// y-stage via MFMA (e @ W0^T, k>=6 zero-padded) + bn0/leaky + swizzled
// scatter, GEMM2 K=384 with acc chained through MFMA C, no barrier.
// ---------------------------------------------------------------------------
__global__ __launch_bounds__(128, 3) void mlp_mfma(
    const f32x4* __restrict__ xt, const int* __restrict__ idx,
    const _Float16* __restrict__ w0f, const float* __restrict__ bn0s,
    const float* __restrict__ bn0b, const _Float16* __restrict__ w1g,
    const float* __restrict__ bn1s, const float* __restrict__ bn1b,
    const float* __restrict__ wc, const float* __restrict__ bncs,
    const float* __restrict__ bncb, float* __restrict__ out) {
    __shared__ __align__(16) _Float16 yL[2][80 * YSTRIDE];
    __shared__ __align__(16) half8 eL[2][80];
    const int wave = threadIdx.x >> 6;
    const int lane = threadIdx.x & 63;
    const int q = lane >> 4, c = lane & 15;
    const int gw = blockIdx.x * 2 + wave;     // 0..4095
    const int b = gw >> 9;                    // 512 waves per batch
    const int P0 = (gw & 511) * 4;
    _Float16* yw = yL[wave];
    half8* ew = eL[wave];
    const f32x4* xtb = xt + (b << 11);

    // ---- e-stage: 1 b128 gather per edge ----
    {
        const int k = lane >> 2, pt = lane & 3;
        const int n = P0 + pt;
        const int j = idx[(b * 2048 + n) * 20 + k];
        const f32x4 cc = xtb[n];
        const f32x4 nb = xtb[j];
        half8 ev;
        ev[0] = (_Float16)(nb[0] - cc[0]); ev[1] = (_Float16)(nb[1] - cc[1]);
        ev[2] = (_Float16)(nb[2] - cc[2]); ev[3] = (_Float16)cc[0];
        ev[4] = (_Float16)cc[1];           ev[5] = (_Float16)cc[2];
        ev[6] = (_Float16)0.f;             ev[7] = (_Float16)0.f;
        ew[lane] = ev;
    }
    if (lane < 16) {
        const int el = 64 + lane;
        const int k = el >> 2, pt = el & 3;
        const int n = P0 + pt;
        const int j = idx[(b * 2048 + n) * 20 + k];
        const f32x4 cc = xtb[n];
        const f32x4 nb = xtb[j];
        half8 ev;
        ev[0] = (_Float16)(nb[0] - cc[0]); ev[1] = (_Float16)(nb[1] - cc[1]);
        ev[2] = (_Float16)(nb[2] - cc[2]); ev[3] = (_Float16)cc[0];
        ev[4] = (_Float16)cc[1];           ev[5] = (_Float16)cc[2];
        ev[6] = (_Float16)0.f;             ev[7] = (_Float16)0.f;
        ew[el] = ev;
    }

    // ---- y-stage via MFMA: y_raw = e @ W0^T, bn0+leaky, swizzled scatter --
    const half8* w0f8 = (const half8*)w0f;
    const half8 z8 = h8zero();
    half8 B1[4];
    float s0v[4], b0v[4];
#pragma unroll
    for (int nt = 0; nt < 4; ++nt) {
        const half8 v = w0f8[nt * 16 + c];
        B1[nt] = (q == 0) ? v : z8;
        s0v[nt] = bn0s[16 * nt + c];
        b0v[nt] = bn0b[16 * nt + c];
    }
#pragma unroll
    for (int mt = 0; mt < 5; ++mt) {
        const half8 ev = ew[16 * mt + c];
        const half8 Ae = (q == 0) ? ev : z8;
        const int ebase = 16 * mt + 4 * q;
#pragma unroll
        for (int nt = 0; nt < 4; ++nt) {
            f32x4 D = {0.f, 0.f, 0.f, 0.f};
            D = __builtin_amdgcn_mfma_f32_16x16x32_f16(Ae, B1[nt], D, 0, 0, 0);
#pragma unroll
            for (int r = 0; r < 4; ++r) {
                float v = D[r] * s0v[nt] + b0v[nt];
                v = fmaxf(v, NEGSLOPE * v);
                const int edge = ebase + r;
                yw[edge * YSTRIDE + ((16 * nt + c) ^ (edge & 0x38))] =
                    (_Float16)v;
            }
        }
    }

    // ---- GEMM2: K=384, acc chained through MFMA C (verified) ----
    const half8* w1g8 = (const half8*)w1g;

    f32x4 acc[5][4];  // [m][t4], u = 16*t4 + c, edge row = 4q + r
#pragma unroll
    for (int mm = 0; mm < 5; ++mm)
#pragma unroll
        for (int t4 = 0; t4 < 4; ++t4) acc[mm][t4] = (f32x4){0.f, 0.f, 0.f, 0.f};

#pragma unroll 1
    for (int i6 = 0; i6 < 6; ++i6) {
        _Float16 es[5];
#pragma unroll
        for (int mm = 0; mm < 5; ++mm)
            es[mm] = ((const _Float16*)(ew + 16 * mm + c))[i6];
#pragma unroll
        for (int ks2 = 0; ks2 < 2; ++ks2) {
            const int ks = 2 * i6 + ks2;
            half8 B[4];
#pragma unroll
            for (int t4 = 0; t4 < 4; ++t4)
                B[t4] = w1g8[(ks * 4 + t4) * 64 + lane];
#pragma unroll
            for (int mm = 0; mm < 5; ++mm) {
                const int rrow = 16 * mm + c;
                const half8 Af = *(const half8*)&yw[rrow * YSTRIDE +
                                                    ((32 * ks2 + 8 * q) ^ (rrow & 0x38))];
                const half8 An = Af * es[mm];
#pragma unroll
                for (int t4 = 0; t4 < 4; ++t4)
                    acc[mm][t4] = __builtin_amdgcn_mfma_f32_16x16x32_f16(
                        An, B[t4], acc[mm][t4], 0, 0, 0);
            }
        }
    }

    // ---- bn1 + leaky + max over k (k = 4m+q) ----
    float bs1[4], bb1[4];
#pragma unroll
    for (int t4 = 0; t4 < 4; ++t4) {
        bs1[t4] = bn1s[16 * t4 + c];
        bb1[t4] = bn1b[16 * t4 + c];
    }

    float x1[4][4];  // [pt r][t4]
#pragma unroll
    for (int r = 0; r < 4; ++r)
#pragma unroll
        for (int t4 = 0; t4 < 4; ++t4) {
            float v = NINF;
#pragma unroll
            for (int mm = 0; mm < 5; ++mm) {
                float w = acc[mm][t4][r] * bs1[t4] + bb1[t4];
                w = fmaxf(w, NEGSLOPE * w);
                v = fmaxf(v, w);
            }
            v = fmaxf(v, __shfl_xor(v, 16, 64));
            v = fmaxf(v, __shfl_xor(v, 32, 64));
            x1[r][t4] = v;
        }

    // ---- head: z[pt][co] = leaky(bnc(sum_u x1*wc)) ----
    float wcv[3][4];
#pragma unroll
    for (int co = 0; co < 3; ++co)
#pragma unroll
        for (int t4 = 0; t4 < 4; ++t4) wcv[co][t4] = wc[co * 64 + 16 * t4 + c];

    float part[4][3];
#pragma unroll
    for (int r = 0; r < 4; ++r)
#pragma unroll
        for (int co = 0; co < 3; ++co) {
            float s = x1[r][0] * wcv[co][0] + x1[r][1] * wcv[co][1] +
                      x1[r][2] * wcv[co][2] + x1[r][3] * wcv[co][3];
#pragma unroll
            for (int d = 1; d < 16; d <<= 1) s += __shfl_xor(s, d, 64);
            part[r][co] = s;
        }

    if (c == 0 && q < 3) {
        const float sc = bncs[q], bc = bncb[q];
#pragma unroll
        for (int r = 0; r < 4; ++r) {
            float z = part[r][q] * sc + bc;
            z = fmaxf(z, NEGSLOPE * z);
            out[(b * 3 + q) * 2048 + P0 + r] = z;
        }
    }
}

// ---------------------------------------------------------------------------
extern "C" void kernel_launch(void* const* d_in, const int* in_sizes, int n_in,
                              void* d_out, int out_size, void* d_ws, size_t ws_size,
                              hipStream_t stream) {
    const float* x    = (const float*)d_in[0];
    const float* W0   = (const float*)d_in[1];
    const float* bn0s = (const float*)d_in[2];
    const float* bn0b = (const float*)d_in[3];
    const float* W1   = (const float*)d_in[4];
    const float* bn1s = (const float*)d_in[5];
    const float* bn1b = (const float*)d_in[6];
    const float* Wc   = (const float*)d_in[7];
    const float* bncs = (const float*)d_in[8];
    const float* bncb = (const float*)d_in[9];

    _Float16* w1g = (_Float16*)d_ws;                     // 48 KiB @ 0
    _Float16* w0f = (_Float16*)((char*)d_ws + 49152);    // 1 KiB
    f32x4* xt = (f32x4*)((char*)d_ws + 65536);           // 256 KiB
    int* idx = (int*)((char*)d_ws + 327680);             // 1.25 MiB

    topk_kernel<<<2056, 256, 0, stream>>>(x, idx, W1, w1g, W0, w0f, xt);
    mlp_mfma<<<2048, 128, 0, stream>>>(xt, idx, w0f, bn0s, bn0b, w1g,
                                       bn1s, bn1b, Wc, bncs, bncb,
                                       (float*)d_out);
}

// Round 2
// 161.679 us; speedup vs baseline: 1.0859x; 1.0859x over previous
//
#include <hip/hip_runtime.h>

#define NEGSLOPE 0.2f
#define NINF (-3.4e38f)

typedef _Float16 half8 __attribute__((ext_vector_type(8)));
typedef float f32x4 __attribute__((ext_vector_type(4)));
typedef unsigned long long u64;

#define YSTRIDE 72  // f16 units; row stride 144 B (16B-aligned for b128)

__device__ __forceinline__ half8 h8zero() {
    half8 z;
#pragma unroll
    for (int i = 0; i < 8; ++i) z[i] = (_Float16)0.f;
    return z;
}

__device__ __forceinline__ unsigned umin(unsigned a, unsigned b) { return a < b ? a : b; }
__device__ __forceinline__ unsigned umax(unsigned a, unsigned b) { return a > b ? a : b; }

// branchless sorted top-4 insert; dropped element feeds g5 (5th-smallest guard)
__device__ __forceinline__ void insert4(unsigned& r0, unsigned& r1, unsigned& r2,
                                        unsigned& r3, unsigned& g5, unsigned p) {
    unsigned q0 = umin(r0, p); p = umax(r0, p); r0 = q0;
    unsigned q1 = umin(r1, p); p = umax(r1, p); r1 = q1;
    unsigned q2 = umin(r2, p); p = umax(r2, p); r2 = q2;
    unsigned q3 = umin(r3, p); p = umax(r3, p); r3 = q3;
    g5 = umin(g5, p);
}

// ---------------------------------------------------------------------------
// topk v14 (BITONIC x2, 2 rows/wave): one wave handles rows (n0, n0+1) of one
// batch. The 3x2048 slab loads are shared between both rows (halves VMEM
// issue vs v12) and the two independent insert/merge chains double in-wave
// ILP where v12 idled ~45% of issue slots. Candidate key unchanged:
// (bits(d^2) & ~2047) | j. Scan: per-lane sorted top-4 + g5 guard per row,
// #pragma unroll 8 to cap in-flight loads (v13 lesson: full unroll -> 96
// live load regs -> 176 VGPR -> occupancy collapse). Merge: v12's verified
// 256-element bitonic, A/B interleaved (8 shfl_xor per CROSS substep, same
// 21-substep serial depth). Ranks 0..19 = lanes 0..4 -> one int4 store per
// row. Guard + rare exact fallback (~0.1% rows) identical to v12, with
// unroll 4 on the cold inner loop to keep worst-path VGPR down.
// Blocks >= 2048: prep path (w1g, w0f, xt) unchanged.
// ---------------------------------------------------------------------------
template <int CTRL>
__device__ __forceinline__ unsigned dpp_movm(unsigned v) {
    return (unsigned)__builtin_amdgcn_update_dpp(-1, (int)v, CTRL, 0xF, 0xF, false);
}

__global__ __launch_bounds__(256) void topk_kernel(
    const float* __restrict__ x, int* __restrict__ idx_out,
    const float* __restrict__ w1, _Float16* __restrict__ w1g,
    const float* __restrict__ w0, _Float16* __restrict__ w0f,
    f32x4* __restrict__ xt) {
    if (blockIdx.x >= 2048) {
        const int pid = blockIdx.x - 2048;   // 0..7
        int tid = pid * 256 + threadIdx.x;
#pragma unroll
        for (int it = 0; it < 12; ++it, tid += 2048) {
            int j = tid & 7;
            int L = (tid >> 3) & 63;
            int r = tid >> 9;          // r = ks*4 + t4
            int t4 = r & 3;
            int ks = r >> 2;
            int q = L >> 4, c = L & 15;
            int i = ks >> 1;
            int o = 32 * (ks & 1) + 8 * q + j;
            int u = 16 * t4 + c;
            w1g[tid] = (_Float16)w1[(u * 6 + i) * 64 + o];
        }
        if (pid == 0) {
#pragma unroll
            for (int s = 0; s < 2; ++s) {
                int t2 = threadIdx.x * 2 + s;
                int r8 = t2 >> 3, j = t2 & 7;
                w0f[t2] = (j < 6) ? (_Float16)w0[r8 * 6 + j] : (_Float16)0.f;
            }
        }
        int base = pid * 2048;
#pragma unroll
        for (int it = 0; it < 8; ++it) {
            int i = base + it * 256 + threadIdx.x;
            int bb = i >> 11, n = i & 2047;
            const float* xbp = x + bb * 6144;
            xt[i] = (f32x4){xbp[n], xbp[2048 + n], xbp[4096 + n], 0.f};
        }
        return;
    }

    const int wave = threadIdx.x >> 6;
    const int lane = threadIdx.x & 63;
    const int pr = blockIdx.x * 4 + wave;   // 0..8191, one wave = 2 rows
    const int b = pr >> 10;                 // 1024 pairs per batch
    const int n0 = (pr & 1023) * 2;         // even row of the pair
    const float* xb = x + b * 6144;
    const float ax = xb[n0],     ay = xb[2048 + n0], az = xb[4096 + n0];
    const float bx = xb[n0 + 1], by = xb[2049 + n0], bz = xb[4097 + n0];

    unsigned A0 = ~0u, A1 = ~0u, A2 = ~0u, A3 = ~0u, g5A = ~0u;
    unsigned B0 = ~0u, B1 = ~0u, B2 = ~0u, B3 = ~0u, g5B = ~0u;

#pragma unroll 8
    for (int t = 0; t < 32; ++t) {
        const int j = t * 64 + lane;
        const float x0 = xb[j], x1 = xb[2048 + j], x2 = xb[4096 + j];
        const float dxa = x0 - ax, dya = x1 - ay, dza = x2 - az;
        const float dxb = x0 - bx, dyb = x1 - by, dzb = x2 - bz;
        const float dA = dxa * dxa + dya * dya + dza * dza;
        const float dB = dxb * dxb + dyb * dyb + dzb * dzb;
        const unsigned pA = (__float_as_uint(dA) & 0xFFFFF800u) | (unsigned)j;
        const unsigned pB = (__float_as_uint(dB) & 0xFFFFF800u) | (unsigned)j;
        insert4(A0, A1, A2, A3, g5A, pA);
        insert4(B0, B1, B2, B3, g5B, pB);
    }

    // ---- dual bitonic sort of 256 (i = 4*lane + slot), stages 1-2 free ----
    if (lane & 1) {  // odd lanes: reverse to descending (stage-2 postcondition)
        unsigned t0;
        t0 = A0; A0 = A3; A3 = t0;  t0 = A1; A1 = A2; A2 = t0;
        t0 = B0; B0 = B3; B3 = t0;  t0 = B1; B1 = B2; B2 = t0;
    }

#define CROSS2(DL, KK)                                                        \
    {                                                                         \
        const bool asc = ((lane >> ((KK) - 2)) & 1) == 0;                     \
        const bool low = (lane & (DL)) == 0;                                  \
        const bool selmin = (asc == low);                                     \
        const unsigned pa0 = (unsigned)__shfl_xor((int)A0, (DL), 64);         \
        const unsigned pa1 = (unsigned)__shfl_xor((int)A1, (DL), 64);         \
        const unsigned pa2 = (unsigned)__shfl_xor((int)A2, (DL), 64);         \
        const unsigned pa3 = (unsigned)__shfl_xor((int)A3, (DL), 64);         \
        const unsigned pb0 = (unsigned)__shfl_xor((int)B0, (DL), 64);         \
        const unsigned pb1 = (unsigned)__shfl_xor((int)B1, (DL), 64);         \
        const unsigned pb2 = (unsigned)__shfl_xor((int)B2, (DL), 64);         \
        const unsigned pb3 = (unsigned)__shfl_xor((int)B3, (DL), 64);         \
        A0 = selmin ? umin(A0, pa0) : umax(A0, pa0);                          \
        A1 = selmin ? umin(A1, pa1) : umax(A1, pa1);                          \
        A2 = selmin ? umin(A2, pa2) : umax(A2, pa2);                          \
        A3 = selmin ? umin(A3, pa3) : umax(A3, pa3);                          \
        B0 = selmin ? umin(B0, pb0) : umax(B0, pb0);                          \
        B1 = selmin ? umin(B1, pb1) : umax(B1, pb1);                          \
        B2 = selmin ? umin(B2, pb2) : umax(B2, pb2);                          \
        B3 = selmin ? umin(B3, pb3) : umax(B3, pb3);                          \
    }
#define INLANE2(KK)                                                           \
    {                                                                         \
        const bool asc = ((lane >> ((KK) - 2)) & 1) == 0;                     \
        { unsigned lo = umin(A0, A2), hi = umax(A0, A2);                      \
          A0 = asc ? lo : hi; A2 = asc ? hi : lo; }                           \
        { unsigned lo = umin(A1, A3), hi = umax(A1, A3);                      \
          A1 = asc ? lo : hi; A3 = asc ? hi : lo; }                           \
        { unsigned lo = umin(A0, A1), hi = umax(A0, A1);                      \
          A0 = asc ? lo : hi; A1 = asc ? hi : lo; }                           \
        { unsigned lo = umin(A2, A3), hi = umax(A2, A3);                      \
          A2 = asc ? lo : hi; A3 = asc ? hi : lo; }                           \
        { unsigned lo = umin(B0, B2), hi = umax(B0, B2);                      \
          B0 = asc ? lo : hi; B2 = asc ? hi : lo; }                           \
        { unsigned lo = umin(B1, B3), hi = umax(B1, B3);                      \
          B1 = asc ? lo : hi; B3 = asc ? hi : lo; }                           \
        { unsigned lo = umin(B0, B1), hi = umax(B0, B1);                      \
          B0 = asc ? lo : hi; B1 = asc ? hi : lo; }                           \
        { unsigned lo = umin(B2, B3), hi = umax(B2, B3);                      \
          B2 = asc ? lo : hi; B3 = asc ? hi : lo; }                           \
    }

    CROSS2(1, 3)  INLANE2(3)
    CROSS2(2, 4)  CROSS2(1, 4)  INLANE2(4)
    CROSS2(4, 5)  CROSS2(2, 5)  CROSS2(1, 5)  INLANE2(5)
    CROSS2(8, 6)  CROSS2(4, 6)  CROSS2(2, 6)  CROSS2(1, 6)  INLANE2(6)
    CROSS2(16, 7) CROSS2(8, 7)  CROSS2(4, 7)  CROSS2(2, 7)  CROSS2(1, 7)  INLANE2(7)
    CROSS2(32, 8) CROSS2(16, 8) CROSS2(8, 8)  CROSS2(4, 8)  CROSS2(2, 8)  CROSS2(1, 8)
    INLANE2(8)
#undef CROSS2
#undef INLANE2

    const int obA = (b * 2048 + n0) * 20;
    const int obB = obA + 20;
    // kept 20th-smallest = position 19 = lane 4, slot 3
    const unsigned T20A = (unsigned)__builtin_amdgcn_readlane((int)A3, 4);
    const unsigned T20B = (unsigned)__builtin_amdgcn_readlane((int)B3, 4);
    const u64 badA = __ballot(g5A < T20A);
    const u64 badB = __ballot(g5B < T20B);

    // exact fallback (rare, ~0.1% of rows): 20 rounds of recompute + DPP-min
    auto fallback = [&](float cx, float cy, float cz, int ob) {
        unsigned Tprev = 0u;
#pragma unroll 1
        for (int r = 0; r < 20; ++r) {
            unsigned best = 0xFFFFFFFFu;
#pragma unroll 4
            for (int t = 0; t < 32; ++t) {
                const int j = t * 64 + lane;
                const float dx = xb[j] - cx;
                const float dy = xb[2048 + j] - cy;
                const float dz = xb[4096 + j] - cz;
                const float d = dx * dx + dy * dy + dz * dz;
                const unsigned p = (__float_as_uint(d) & 0xFFFFF800u) | (unsigned)j;
                const bool ok = (r == 0) || (p > Tprev);
                best = umin(best, ok ? p : 0xFFFFFFFFu);
            }
            { unsigned o = dpp_movm<0x111>(best); best = umin(best, o); }
            { unsigned o = dpp_movm<0x112>(best); best = umin(best, o); }
            { unsigned o = dpp_movm<0x114>(best); best = umin(best, o); }
            { unsigned o = dpp_movm<0x118>(best); best = umin(best, o); }
            { unsigned o = dpp_movm<0x142>(best); best = umin(best, o); }
            { unsigned o = dpp_movm<0x143>(best); best = umin(best, o); }
            const unsigned K = (unsigned)__builtin_amdgcn_readlane((int)best, 63);
            if (lane == 0) idx_out[ob + r] = (int)(K & 2047u);
            Tprev = K;
        }
    };

    if (badA == 0) {
        if (lane < 5) {
            int4 v;
            v.x = (int)(A0 & 2047u); v.y = (int)(A1 & 2047u);
            v.z = (int)(A2 & 2047u); v.w = (int)(A3 & 2047u);
            *(int4*)(idx_out + obA + lane * 4) = v;
        }
    } else {
        fallback(ax, ay, az, obA);
    }

    if (badB == 0) {
        if (lane < 5) {
            int4 v;
            v.x = (int)(B0 & 2047u); v.y = (int)(B1 & 2047u);
            v.z = (int)(B2 & 2047u); v.w = (int)(B3 & 2047u);
            *(int4*)(idx_out + obB + lane * 4) = v;
        }
    } else {
        fallback(bx, by, bz, obB);
    }
}

// ---------------------------------------------------------------------------
// mlp v3 (FROZEN, R10/R12-identical): e-stage b128 gathers from xt,
// y-stage via MFMA (e @ W0^T, k>=6 zero-padded) + bn0/leaky + swizzled
// scatter, GEMM2 K=384 with acc chained through MFMA C, no barrier.
// ---------------------------------------------------------------------------
__global__ __launch_bounds__(128, 3) void mlp_mfma(
    const f32x4* __restrict__ xt, const int* __restrict__ idx,
    const _Float16* __restrict__ w0f, const float* __restrict__ bn0s,
    const float* __restrict__ bn0b, const _Float16* __restrict__ w1g,
    const float* __restrict__ bn1s, const float* __restrict__ bn1b,
    const float* __restrict__ wc, const float* __restrict__ bncs,
    const float* __restrict__ bncb, float* __restrict__ out) {
    __shared__ __align__(16) _Float16 yL[2][80 * YSTRIDE];
    __shared__ __align__(16) half8 eL[2][80];
    const int wave = threadIdx.x >> 6;
    const int lane = threadIdx.x & 63;
    const int q = lane >> 4, c = lane & 15;
    const int gw = blockIdx.x * 2 + wave;     // 0..4095
    const int b = gw >> 9;                    // 512 waves per batch
    const int P0 = (gw & 511) * 4;
    _Float16* yw = yL[wave];
    half8* ew = eL[wave];
    const f32x4* xtb = xt + (b << 11);

    // ---- e-stage: 1 b128 gather per edge ----
    {
        const int k = lane >> 2, pt = lane & 3;
        const int n = P0 + pt;
        const int j = idx[(b * 2048 + n) * 20 + k];
        const f32x4 cc = xtb[n];
        const f32x4 nb = xtb[j];
        half8 ev;
        ev[0] = (_Float16)(nb[0] - cc[0]); ev[1] = (_Float16)(nb[1] - cc[1]);
        ev[2] = (_Float16)(nb[2] - cc[2]); ev[3] = (_Float16)cc[0];
        ev[4] = (_Float16)cc[1];           ev[5] = (_Float16)cc[2];
        ev[6] = (_Float16)0.f;             ev[7] = (_Float16)0.f;
        ew[lane] = ev;
    }
    if (lane < 16) {
        const int el = 64 + lane;
        const int k = el >> 2, pt = el & 3;
        const int n = P0 + pt;
        const int j = idx[(b * 2048 + n) * 20 + k];
        const f32x4 cc = xtb[n];
        const f32x4 nb = xtb[j];
        half8 ev;
        ev[0] = (_Float16)(nb[0] - cc[0]); ev[1] = (_Float16)(nb[1] - cc[1]);
        ev[2] = (_Float16)(nb[2] - cc[2]); ev[3] = (_Float16)cc[0];
        ev[4] = (_Float16)cc[1];           ev[5] = (_Float16)cc[2];
        ev[6] = (_Float16)0.f;             ev[7] = (_Float16)0.f;
        ew[el] = ev;
    }

    // ---- y-stage via MFMA: y_raw = e @ W0^T, bn0+leaky, swizzled scatter --
    const half8* w0f8 = (const half8*)w0f;
    const half8 z8 = h8zero();
    half8 B1[4];
    float s0v[4], b0v[4];
#pragma unroll
    for (int nt = 0; nt < 4; ++nt) {
        const half8 v = w0f8[nt * 16 + c];
        B1[nt] = (q == 0) ? v : z8;
        s0v[nt] = bn0s[16 * nt + c];
        b0v[nt] = bn0b[16 * nt + c];
    }
#pragma unroll
    for (int mt = 0; mt < 5; ++mt) {
        const half8 ev = ew[16 * mt + c];
        const half8 Ae = (q == 0) ? ev : z8;
        const int ebase = 16 * mt + 4 * q;
#pragma unroll
        for (int nt = 0; nt < 4; ++nt) {
            f32x4 D = {0.f, 0.f, 0.f, 0.f};
            D = __builtin_amdgcn_mfma_f32_16x16x32_f16(Ae, B1[nt], D, 0, 0, 0);
#pragma unroll
            for (int r = 0; r < 4; ++r) {
                float v = D[r] * s0v[nt] + b0v[nt];
                v = fmaxf(v, NEGSLOPE * v);
                const int edge = ebase + r;
                yw[edge * YSTRIDE + ((16 * nt + c) ^ (edge & 0x38))] =
                    (_Float16)v;
            }
        }
    }

    // ---- GEMM2: K=384, acc chained through MFMA C (verified) ----
    const half8* w1g8 = (const half8*)w1g;

    f32x4 acc[5][4];  // [m][t4], u = 16*t4 + c, edge row = 4q + r
#pragma unroll
    for (int mm = 0; mm < 5; ++mm)
#pragma unroll
        for (int t4 = 0; t4 < 4; ++t4) acc[mm][t4] = (f32x4){0.f, 0.f, 0.f, 0.f};

#pragma unroll 1
    for (int i6 = 0; i6 < 6; ++i6) {
        _Float16 es[5];
#pragma unroll
        for (int mm = 0; mm < 5; ++mm)
            es[mm] = ((const _Float16*)(ew + 16 * mm + c))[i6];
#pragma unroll
        for (int ks2 = 0; ks2 < 2; ++ks2) {
            const int ks = 2 * i6 + ks2;
            half8 B[4];
#pragma unroll
            for (int t4 = 0; t4 < 4; ++t4)
                B[t4] = w1g8[(ks * 4 + t4) * 64 + lane];
#pragma unroll
            for (int mm = 0; mm < 5; ++mm) {
                const int rrow = 16 * mm + c;
                const half8 Af = *(const half8*)&yw[rrow * YSTRIDE +
                                                    ((32 * ks2 + 8 * q) ^ (rrow & 0x38))];
                const half8 An = Af * es[mm];
#pragma unroll
                for (int t4 = 0; t4 < 4; ++t4)
                    acc[mm][t4] = __builtin_amdgcn_mfma_f32_16x16x32_f16(
                        An, B[t4], acc[mm][t4], 0, 0, 0);
            }
        }
    }

    // ---- bn1 + leaky + max over k (k = 4m+q) ----
    float bs1[4], bb1[4];
#pragma unroll
    for (int t4 = 0; t4 < 4; ++t4) {
        bs1[t4] = bn1s[16 * t4 + c];
        bb1[t4] = bn1b[16 * t4 + c];
    }

    float x1[4][4];  // [pt r][t4]
#pragma unroll
    for (int r = 0; r < 4; ++r)
#pragma unroll
        for (int t4 = 0; t4 < 4; ++t4) {
            float v = NINF;
#pragma unroll
            for (int mm = 0; mm < 5; ++mm) {
                float w = acc[mm][t4][r] * bs1[t4] + bb1[t4];
                w = fmaxf(w, NEGSLOPE * w);
                v = fmaxf(v, w);
            }
            v = fmaxf(v, __shfl_xor(v, 16, 64));
            v = fmaxf(v, __shfl_xor(v, 32, 64));
            x1[r][t4] = v;
        }

    // ---- head: z[pt][co] = leaky(bnc(sum_u x1*wc)) ----
    float wcv[3][4];
#pragma unroll
    for (int co = 0; co < 3; ++co)
#pragma unroll
        for (int t4 = 0; t4 < 4; ++t4) wcv[co][t4] = wc[co * 64 + 16 * t4 + c];

    float part[4][3];
#pragma unroll
    for (int r = 0; r < 4; ++r)
#pragma unroll
        for (int co = 0; co < 3; ++co) {
            float s = x1[r][0] * wcv[co][0] + x1[r][1] * wcv[co][1] +
                      x1[r][2] * wcv[co][2] + x1[r][3] * wcv[co][3];
#pragma unroll
            for (int d = 1; d < 16; d <<= 1) s += __shfl_xor(s, d, 64);
            part[r][co] = s;
        }

    if (c == 0 && q < 3) {
        const float sc = bncs[q], bc = bncb[q];
#pragma unroll
        for (int r = 0; r < 4; ++r) {
            float z = part[r][q] * sc + bc;
            z = fmaxf(z, NEGSLOPE * z);
            out[(b * 3 + q) * 2048 + P0 + r] = z;
        }
    }
}

// ---------------------------------------------------------------------------
extern "C" void kernel_launch(void* const* d_in, const int* in_sizes, int n_in,
                              void* d_out, int out_size, void* d_ws, size_t ws_size,
                              hipStream_t stream) {
    const float* x    = (const float*)d_in[0];
    const float* W0   = (const float*)d_in[1];
    const float* bn0s = (const float*)d_in[2];
    const float* bn0b = (const float*)d_in[3];
    const float* W1   = (const float*)d_in[4];
    const float* bn1s = (const float*)d_in[5];
    const float* bn1b = (const float*)d_in[6];
    const float* Wc   = (const float*)d_in[7];
    const float* bncs = (const float*)d_in[8];
    const float* bncb = (const float*)d_in[9];

    _Float16* w1g = (_Float16*)d_ws;                     // 48 KiB @ 0
    _Float16* w0f = (_Float16*)((char*)d_ws + 49152);    // 1 KiB
    f32x4* xt = (f32x4*)((char*)d_ws + 65536);           // 256 KiB
    int* idx = (int*)((char*)d_ws + 327680);             // 1.25 MiB

    topk_kernel<<<2056, 256, 0, stream>>>(x, idx, W1, w1g, W0, w0f, xt);
    mlp_mfma<<<2048, 128, 0, stream>>>(xt, idx, w0f, bn0s, bn0b, w1g,
                                       bn1s, bn1b, Wc, bncs, bncb,
                                       (float*)d_out);
}

// Round 3
// 128.251 us; speedup vs baseline: 1.3690x; 1.2606x over previous
//
#include <hip/hip_runtime.h>

#define NEGSLOPE 0.2f
#define NINF (-3.4e38f)

typedef _Float16 half8 __attribute__((ext_vector_type(8)));
typedef float f32x4 __attribute__((ext_vector_type(4)));
typedef unsigned long long u64;

#define YSTRIDE 72  // f16 units; row stride 144 B (16B-aligned for b128)

__device__ __forceinline__ half8 h8zero() {
    half8 z;
#pragma unroll
    for (int i = 0; i < 8; ++i) z[i] = (_Float16)0.f;
    return z;
}

__device__ __forceinline__ unsigned umin(unsigned a, unsigned b) { return a < b ? a : b; }
__device__ __forceinline__ unsigned umax(unsigned a, unsigned b) { return a > b ? a : b; }

// ---------------------------------------------------------------------------
// topk v15 (= v12 + float4 scan loads): one wave per row, v12's verified
// bitonic merge. ONLY change vs v12: the 3 slab streams are read as
// global_load_dwordx4 (lane covers j = t*256 + 4*lane + s, s=0..3) -- 96
// scalar loads -> 24 x 16B loads, 4x bytes-in-flight per VGPR. v13/v14
// lesson: scan is L1-latency bound; unroll caps kill MLP (36 VGPR, 33%
// VALUBusy), oversized state kills TLP (176 VGPR). Candidate key unchanged:
// (bits(d^2) & ~2047) | j  => identical kept set, order-invariant downstream.
// Merge: per-lane sorted top-4 (i = 4*lane + slot, stages 1-2 free) +
// bitonic stages 3-8 (21 cross-lane substeps, 4 shfl_xor each) + g5k
// exactness guard; ranks 0..19 = lanes 0..4 -> one int4 store. Exact
// fallback (~0.1% rows) identical, same float4 loads.
// Blocks >= 4096: prep path (w1g, w0f, xt) unchanged.
// ---------------------------------------------------------------------------
template <int CTRL>
__device__ __forceinline__ unsigned dpp_movm(unsigned v) {
    return (unsigned)__builtin_amdgcn_update_dpp(-1, (int)v, CTRL, 0xF, 0xF, false);
}

__global__ __launch_bounds__(256) void topk_kernel(
    const float* __restrict__ x, int* __restrict__ idx_out,
    const float* __restrict__ w1, _Float16* __restrict__ w1g,
    const float* __restrict__ w0, _Float16* __restrict__ w0f,
    f32x4* __restrict__ xt) {
    if (blockIdx.x >= 4096) {
        const int pid = blockIdx.x - 4096;   // 0..7
        int tid = pid * 256 + threadIdx.x;
#pragma unroll
        for (int it = 0; it < 12; ++it, tid += 2048) {
            int j = tid & 7;
            int L = (tid >> 3) & 63;
            int r = tid >> 9;          // r = ks*4 + t4
            int t4 = r & 3;
            int ks = r >> 2;
            int q = L >> 4, c = L & 15;
            int i = ks >> 1;
            int o = 32 * (ks & 1) + 8 * q + j;
            int u = 16 * t4 + c;
            w1g[tid] = (_Float16)w1[(u * 6 + i) * 64 + o];
        }
        if (pid == 0) {
#pragma unroll
            for (int s = 0; s < 2; ++s) {
                int t2 = threadIdx.x * 2 + s;
                int r8 = t2 >> 3, j = t2 & 7;
                w0f[t2] = (j < 6) ? (_Float16)w0[r8 * 6 + j] : (_Float16)0.f;
            }
        }
        int base = pid * 2048;
#pragma unroll
        for (int it = 0; it < 8; ++it) {
            int i = base + it * 256 + threadIdx.x;
            int bb = i >> 11, n = i & 2047;
            const float* xbp = x + bb * 6144;
            xt[i] = (f32x4){xbp[n], xbp[2048 + n], xbp[4096 + n], 0.f};
        }
        return;
    }

    const int wave = threadIdx.x >> 6;
    const int lane = threadIdx.x & 63;
    const int row = blockIdx.x * 4 + wave;
    const int b = row >> 11;
    const int n = row & 2047;
    const float* xb = x + b * 6144;
    const float xn0 = xb[n];
    const float xn1 = xb[2048 + n];
    const float xn2 = xb[4096 + n];

    const f32x4* s0 = (const f32x4*)xb;
    const f32x4* s1 = (const f32x4*)(xb + 2048);
    const f32x4* s2 = (const f32x4*)(xb + 4096);

    unsigned r0 = 0xFFFFFFFFu, r1 = 0xFFFFFFFFu;
    unsigned r2 = 0xFFFFFFFFu, r3 = 0xFFFFFFFFu;   // per-lane top-4, sorted
    unsigned g5k = 0xFFFFFFFFu;                    // per-lane 5th-smallest

#pragma unroll
    for (int t = 0; t < 8; ++t) {
        const f32x4 v0 = s0[t * 64 + lane];
        const f32x4 v1 = s1[t * 64 + lane];
        const f32x4 v2 = s2[t * 64 + lane];
        const int jb = t * 256 + lane * 4;
#pragma unroll
        for (int s = 0; s < 4; ++s) {
            const float dx = v0[s] - xn0;
            const float dy = v1[s] - xn1;
            const float dz = v2[s] - xn2;
            const float d = dx * dx + dy * dy + dz * dz;
            unsigned p = (__float_as_uint(d) & 0xFFFFF800u) | (unsigned)(jb + s);
            // branchless sorted insert (drop largest into g5k)
            unsigned q0 = umin(r0, p); p = umax(r0, p); r0 = q0;
            unsigned q1 = umin(r1, p); p = umax(r1, p); r1 = q1;
            unsigned q2 = umin(r2, p); p = umax(r2, p); r2 = q2;
            unsigned q3 = umin(r3, p); p = umax(r3, p); r3 = q3;
            g5k = umin(g5k, p);
        }
    }

    // ---- bitonic sort of 256 (i = 4*lane + slot), stages 1-2 free ----
    if (lane & 1) {  // odd lanes: reverse to descending (stage-2 postcondition)
        unsigned t0 = r0; r0 = r3; r3 = t0;
        unsigned t1 = r1; r1 = r2; r2 = t1;
    }

#define CROSS(DL, KK)                                                         \
    {                                                                         \
        const bool asc = ((lane >> ((KK) - 2)) & 1) == 0;                     \
        const bool low = (lane & (DL)) == 0;                                  \
        const bool selmin = (asc == low);                                     \
        const unsigned p0 = (unsigned)__shfl_xor((int)r0, (DL), 64);          \
        const unsigned p1 = (unsigned)__shfl_xor((int)r1, (DL), 64);          \
        const unsigned p2 = (unsigned)__shfl_xor((int)r2, (DL), 64);          \
        const unsigned p3 = (unsigned)__shfl_xor((int)r3, (DL), 64);          \
        r0 = selmin ? umin(r0, p0) : umax(r0, p0);                            \
        r1 = selmin ? umin(r1, p1) : umax(r1, p1);                            \
        r2 = selmin ? umin(r2, p2) : umax(r2, p2);                            \
        r3 = selmin ? umin(r3, p3) : umax(r3, p3);                            \
    }
#define INLANE(KK)                                                            \
    {                                                                         \
        const bool asc = ((lane >> ((KK) - 2)) & 1) == 0;                     \
        { unsigned lo = umin(r0, r2), hi = umax(r0, r2);                      \
          r0 = asc ? lo : hi; r2 = asc ? hi : lo; }                           \
        { unsigned lo = umin(r1, r3), hi = umax(r1, r3);                      \
          r1 = asc ? lo : hi; r3 = asc ? hi : lo; }                           \
        { unsigned lo = umin(r0, r1), hi = umax(r0, r1);                      \
          r0 = asc ? lo : hi; r1 = asc ? hi : lo; }                           \
        { unsigned lo = umin(r2, r3), hi = umax(r2, r3);                      \
          r2 = asc ? lo : hi; r3 = asc ? hi : lo; }                           \
    }

    CROSS(1, 3)  INLANE(3)
    CROSS(2, 4)  CROSS(1, 4)  INLANE(4)
    CROSS(4, 5)  CROSS(2, 5)  CROSS(1, 5)  INLANE(5)
    CROSS(8, 6)  CROSS(4, 6)  CROSS(2, 6)  CROSS(1, 6)  INLANE(6)
    CROSS(16, 7) CROSS(8, 7)  CROSS(4, 7)  CROSS(2, 7)  CROSS(1, 7)  INLANE(7)
    CROSS(32, 8) CROSS(16, 8) CROSS(8, 8)  CROSS(4, 8)  CROSS(2, 8)  CROSS(1, 8)
    INLANE(8)
#undef CROSS
#undef INLANE

    const int out_base = row * 20;
    // kept 20th-smallest = position 19 = lane 4, slot 3
    const unsigned T20p = (unsigned)__builtin_amdgcn_readlane((int)r3, 4);
    const u64 bad = __ballot(g5k < T20p);

    if (bad == 0) {
        if (lane < 5) {
            int4 v;
            v.x = (int)(r0 & 2047u); v.y = (int)(r1 & 2047u);
            v.z = (int)(r2 & 2047u); v.w = (int)(r3 & 2047u);
            *(int4*)(idx_out + out_base + lane * 4) = v;
        }
    } else {
        // exact fallback (rare, ~0.1% of rows): 20 rounds of recompute + DPP-min
        unsigned Tprev = 0u;
#pragma unroll 1
        for (int r = 0; r < 20; ++r) {
            unsigned best = 0xFFFFFFFFu;
#pragma unroll
            for (int t = 0; t < 8; ++t) {
                const f32x4 v0 = s0[t * 64 + lane];
                const f32x4 v1 = s1[t * 64 + lane];
                const f32x4 v2 = s2[t * 64 + lane];
                const int jb = t * 256 + lane * 4;
#pragma unroll
                for (int s = 0; s < 4; ++s) {
                    const float dx = v0[s] - xn0;
                    const float dy = v1[s] - xn1;
                    const float dz = v2[s] - xn2;
                    const float d = dx * dx + dy * dy + dz * dz;
                    const unsigned p =
                        (__float_as_uint(d) & 0xFFFFF800u) | (unsigned)(jb + s);
                    const bool ok = (r == 0) || (p > Tprev);
                    best = umin(best, ok ? p : 0xFFFFFFFFu);
                }
            }
            { unsigned o = dpp_movm<0x111>(best); best = umin(best, o); }
            { unsigned o = dpp_movm<0x112>(best); best = umin(best, o); }
            { unsigned o = dpp_movm<0x114>(best); best = umin(best, o); }
            { unsigned o = dpp_movm<0x118>(best); best = umin(best, o); }
            { unsigned o = dpp_movm<0x142>(best); best = umin(best, o); }
            { unsigned o = dpp_movm<0x143>(best); best = umin(best, o); }
            const unsigned K = (unsigned)__builtin_amdgcn_readlane((int)best, 63);
            if (lane == 0) idx_out[out_base + r] = (int)(K & 2047u);
            Tprev = K;
        }
    }
}

// ---------------------------------------------------------------------------
// mlp v3 (FROZEN, R10/R12-identical): e-stage b128 gathers from xt,
// y-stage via MFMA (e @ W0^T, k>=6 zero-padded) + bn0/leaky + swizzled
// scatter, GEMM2 K=384 with acc chained through MFMA C, no barrier.
// ---------------------------------------------------------------------------
__global__ __launch_bounds__(128, 3) void mlp_mfma(
    const f32x4* __restrict__ xt, const int* __restrict__ idx,
    const _Float16* __restrict__ w0f, const float* __restrict__ bn0s,
    const float* __restrict__ bn0b, const _Float16* __restrict__ w1g,
    const float* __restrict__ bn1s, const float* __restrict__ bn1b,
    const float* __restrict__ wc, const float* __restrict__ bncs,
    const float* __restrict__ bncb, float* __restrict__ out) {
    __shared__ __align__(16) _Float16 yL[2][80 * YSTRIDE];
    __shared__ __align__(16) half8 eL[2][80];
    const int wave = threadIdx.x >> 6;
    const int lane = threadIdx.x & 63;
    const int q = lane >> 4, c = lane & 15;
    const int gw = blockIdx.x * 2 + wave;     // 0..4095
    const int b = gw >> 9;                    // 512 waves per batch
    const int P0 = (gw & 511) * 4;
    _Float16* yw = yL[wave];
    half8* ew = eL[wave];
    const f32x4* xtb = xt + (b << 11);

    // ---- e-stage: 1 b128 gather per edge ----
    {
        const int k = lane >> 2, pt = lane & 3;
        const int n = P0 + pt;
        const int j = idx[(b * 2048 + n) * 20 + k];
        const f32x4 cc = xtb[n];
        const f32x4 nb = xtb[j];
        half8 ev;
        ev[0] = (_Float16)(nb[0] - cc[0]); ev[1] = (_Float16)(nb[1] - cc[1]);
        ev[2] = (_Float16)(nb[2] - cc[2]); ev[3] = (_Float16)cc[0];
        ev[4] = (_Float16)cc[1];           ev[5] = (_Float16)cc[2];
        ev[6] = (_Float16)0.f;             ev[7] = (_Float16)0.f;
        ew[lane] = ev;
    }
    if (lane < 16) {
        const int el = 64 + lane;
        const int k = el >> 2, pt = el & 3;
        const int n = P0 + pt;
        const int j = idx[(b * 2048 + n) * 20 + k];
        const f32x4 cc = xtb[n];
        const f32x4 nb = xtb[j];
        half8 ev;
        ev[0] = (_Float16)(nb[0] - cc[0]); ev[1] = (_Float16)(nb[1] - cc[1]);
        ev[2] = (_Float16)(nb[2] - cc[2]); ev[3] = (_Float16)cc[0];
        ev[4] = (_Float16)cc[1];           ev[5] = (_Float16)cc[2];
        ev[6] = (_Float16)0.f;             ev[7] = (_Float16)0.f;
        ew[el] = ev;
    }

    // ---- y-stage via MFMA: y_raw = e @ W0^T, bn0+leaky, swizzled scatter --
    const half8* w0f8 = (const half8*)w0f;
    const half8 z8 = h8zero();
    half8 B1[4];
    float s0v[4], b0v[4];
#pragma unroll
    for (int nt = 0; nt < 4; ++nt) {
        const half8 v = w0f8[nt * 16 + c];
        B1[nt] = (q == 0) ? v : z8;
        s0v[nt] = bn0s[16 * nt + c];
        b0v[nt] = bn0b[16 * nt + c];
    }
#pragma unroll
    for (int mt = 0; mt < 5; ++mt) {
        const half8 ev = ew[16 * mt + c];
        const half8 Ae = (q == 0) ? ev : z8;
        const int ebase = 16 * mt + 4 * q;
#pragma unroll
        for (int nt = 0; nt < 4; ++nt) {
            f32x4 D = {0.f, 0.f, 0.f, 0.f};
            D = __builtin_amdgcn_mfma_f32_16x16x32_f16(Ae, B1[nt], D, 0, 0, 0);
#pragma unroll
            for (int r = 0; r < 4; ++r) {
                float v = D[r] * s0v[nt] + b0v[nt];
                v = fmaxf(v, NEGSLOPE * v);
                const int edge = ebase + r;
                yw[edge * YSTRIDE + ((16 * nt + c) ^ (edge & 0x38))] =
                    (_Float16)v;
            }
        }
    }

    // ---- GEMM2: K=384, acc chained through MFMA C (verified) ----
    const half8* w1g8 = (const half8*)w1g;

    f32x4 acc[5][4];  // [m][t4], u = 16*t4 + c, edge row = 4q + r
#pragma unroll
    for (int mm = 0; mm < 5; ++mm)
#pragma unroll
        for (int t4 = 0; t4 < 4; ++t4) acc[mm][t4] = (f32x4){0.f, 0.f, 0.f, 0.f};

#pragma unroll 1
    for (int i6 = 0; i6 < 6; ++i6) {
        _Float16 es[5];
#pragma unroll
        for (int mm = 0; mm < 5; ++mm)
            es[mm] = ((const _Float16*)(ew + 16 * mm + c))[i6];
#pragma unroll
        for (int ks2 = 0; ks2 < 2; ++ks2) {
            const int ks = 2 * i6 + ks2;
            half8 B[4];
#pragma unroll
            for (int t4 = 0; t4 < 4; ++t4)
                B[t4] = w1g8[(ks * 4 + t4) * 64 + lane];
#pragma unroll
            for (int mm = 0; mm < 5; ++mm) {
                const int rrow = 16 * mm + c;
                const half8 Af = *(const half8*)&yw[rrow * YSTRIDE +
                                                    ((32 * ks2 + 8 * q) ^ (rrow & 0x38))];
                const half8 An = Af * es[mm];
#pragma unroll
                for (int t4 = 0; t4 < 4; ++t4)
                    acc[mm][t4] = __builtin_amdgcn_mfma_f32_16x16x32_f16(
                        An, B[t4], acc[mm][t4], 0, 0, 0);
            }
        }
    }

    // ---- bn1 + leaky + max over k (k = 4m+q) ----
    float bs1[4], bb1[4];
#pragma unroll
    for (int t4 = 0; t4 < 4; ++t4) {
        bs1[t4] = bn1s[16 * t4 + c];
        bb1[t4] = bn1b[16 * t4 + c];
    }

    float x1[4][4];  // [pt r][t4]
#pragma unroll
    for (int r = 0; r < 4; ++r)
#pragma unroll
        for (int t4 = 0; t4 < 4; ++t4) {
            float v = NINF;
#pragma unroll
            for (int mm = 0; mm < 5; ++mm) {
                float w = acc[mm][t4][r] * bs1[t4] + bb1[t4];
                w = fmaxf(w, NEGSLOPE * w);
                v = fmaxf(v, w);
            }
            v = fmaxf(v, __shfl_xor(v, 16, 64));
            v = fmaxf(v, __shfl_xor(v, 32, 64));
            x1[r][t4] = v;
        }

    // ---- head: z[pt][co] = leaky(bnc(sum_u x1*wc)) ----
    float wcv[3][4];
#pragma unroll
    for (int co = 0; co < 3; ++co)
#pragma unroll
        for (int t4 = 0; t4 < 4; ++t4) wcv[co][t4] = wc[co * 64 + 16 * t4 + c];

    float part[4][3];
#pragma unroll
    for (int r = 0; r < 4; ++r)
#pragma unroll
        for (int co = 0; co < 3; ++co) {
            float s = x1[r][0] * wcv[co][0] + x1[r][1] * wcv[co][1] +
                      x1[r][2] * wcv[co][2] + x1[r][3] * wcv[co][3];
#pragma unroll
            for (int d = 1; d < 16; d <<= 1) s += __shfl_xor(s, d, 64);
            part[r][co] = s;
        }

    if (c == 0 && q < 3) {
        const float sc = bncs[q], bc = bncb[q];
#pragma unroll
        for (int r = 0; r < 4; ++r) {
            float z = part[r][q] * sc + bc;
            z = fmaxf(z, NEGSLOPE * z);
            out[(b * 3 + q) * 2048 + P0 + r] = z;
        }
    }
}

// ---------------------------------------------------------------------------
extern "C" void kernel_launch(void* const* d_in, const int* in_sizes, int n_in,
                              void* d_out, int out_size, void* d_ws, size_t ws_size,
                              hipStream_t stream) {
    const float* x    = (const float*)d_in[0];
    const float* W0   = (const float*)d_in[1];
    const float* bn0s = (const float*)d_in[2];
    const float* bn0b = (const float*)d_in[3];
    const float* W1   = (const float*)d_in[4];
    const float* bn1s = (const float*)d_in[5];
    const float* bn1b = (const float*)d_in[6];
    const float* Wc   = (const float*)d_in[7];
    const float* bncs = (const float*)d_in[8];
    const float* bncb = (const float*)d_in[9];

    _Float16* w1g = (_Float16*)d_ws;                     // 48 KiB @ 0
    _Float16* w0f = (_Float16*)((char*)d_ws + 49152);    // 1 KiB
    f32x4* xt = (f32x4*)((char*)d_ws + 65536);           // 256 KiB
    int* idx = (int*)((char*)d_ws + 327680);             // 1.25 MiB

    topk_kernel<<<4104, 256, 0, stream>>>(x, idx, W1, w1g, W0, w0f, xt);
    mlp_mfma<<<2048, 128, 0, stream>>>(xt, idx, w0f, bn0s, bn0b, w1g,
                                       bn1s, bn1b, Wc, bncs, bncb,
                                       (float*)d_out);
}